// Round 5
// baseline (520.741 us; speedup 1.0000x reference)
//
#include <hip/hip_runtime.h>
#include <hip/hip_bf16.h>

typedef unsigned short ushort_t;
typedef __attribute__((ext_vector_type(8))) short short8;
typedef __attribute__((ext_vector_type(8))) unsigned short ushort8;
typedef __attribute__((ext_vector_type(4))) float f32x4;

#define MFMA16(a,b,c) __builtin_amdgcn_mfma_f32_16x16x32_bf16((a),(b),(c),0,0,0)

__device__ __forceinline__ ushort_t f2bf(float f) {
  unsigned int u = __builtin_bit_cast(unsigned int, f);
  u += 0x7FFFu + ((u >> 16) & 1u);
  return (ushort_t)(u >> 16);
}
__device__ __forceinline__ unsigned int pack2bf(float a, float b) {
  unsigned int ua = __builtin_bit_cast(unsigned int, a);
  unsigned int ub = __builtin_bit_cast(unsigned int, b);
  ua += 0x7FFFu + ((ua >> 16) & 1u);
  ub += 0x7FFFu + ((ub >> 16) & 1u);
  return (ua >> 16) | (ub & 0xFFFF0000u);
}

// Problem dims
#define DMd 1024
#define DPd 128
#define PPd 256

// Workspace layout (ushort element offsets unless noted)
// KWqExt fragments: [chunk 8][ct 17][k4 4][lane 64][8]  (272 x 1024 bf16)
#define KWQ_OFF 0
#define KWQ_SIZE (8*17*4*512)          // 278528
// VWo fragments: [ctg 64][k8 8][lane 64][8]             (256 x 1024 bf16)
#define VWO_OFF KWQ_SIZE
#define VWO_SIZE (64*8*512)            // 262144
#define KV_BYTE_OFF ((size_t)(KWQ_SIZE + VWO_SIZE) * 2)  // then: k [256][128] f32, vT [128][256] f32

// ---------------------------------------------------------------------------
// prep1: k = prim @ Wk^T (row-major [256][128]) and vT = (prim @ Wv^T)^T
// ---------------------------------------------------------------------------
__global__ __launch_bounds__(256) void prep1_kernel(
    const float* __restrict__ prim, const float* __restrict__ Wk,
    const float* __restrict__ Wv, ushort_t* __restrict__ ws) {
  __shared__ __align__(16) float Wl[128 * 132];
  __shared__ __align__(16) float pl[2 * 128];
  const int t = threadIdx.x;
  const int mat = blockIdx.x & 1;
  const int p0 = (blockIdx.x >> 1) * 2;
  const float* W = mat ? Wv : Wk;
  #pragma unroll
  for (int i = 0; i < 16; ++i) {
    int w = (i * 256 + t) * 4;
    int row = w >> 7, col = w & 127;
    *(float4*)&Wl[row * 132 + col] = *(const float4*)(W + w);
  }
  if (t < 64) {
    int row = t >> 5, col = (t & 31) * 4;
    *(float4*)&pl[row * 128 + col] = *(const float4*)(prim + (p0 + row) * 128 + col);
  }
  __syncthreads();
  const int d = t & 127, slot = t >> 7;
  float a0 = 0.f, a1 = 0.f, a2 = 0.f, a3 = 0.f;
  #pragma unroll
  for (int j = 0; j < 128; j += 4) {
    float4 w4 = *(const float4*)&Wl[d * 132 + j];
    float4 p4 = *(const float4*)&pl[slot * 128 + j];
    a0 += w4.x * p4.x; a1 += w4.y * p4.y; a2 += w4.z * p4.z; a3 += w4.w * p4.w;
  }
  float r = (a0 + a1) + (a2 + a3);
  float* kf = (float*)((char*)ws + KV_BYTE_OFF);
  float* vT = kf + 32768;
  if (mat == 0) kf[(p0 + slot) * 128 + d] = r;
  else          vT[d * 256 + p0 + slot] = r;
}

// ---------------------------------------------------------------------------
// prep2: 264 blocks; emits frag-major KWqExt / VWo.
// ---------------------------------------------------------------------------
__global__ __launch_bounds__(256) void prep2_kernel(
    const float* __restrict__ Wq, const float* __restrict__ Wo,
    const float* __restrict__ gate_w, ushort_t* __restrict__ ws) {
  const float* kf = (const float*)((const char*)ws + KV_BYTE_OFF);
  const float* vT = kf + 32768;
  __shared__ __align__(16) float tile[8 * 128];
  const int b = blockIdx.x, t = threadIdx.x;
  float acc[8];
  #pragma unroll
  for (int j = 0; j < 8; ++j) acc[j] = 0.f;
  if (b < 136) {
    const int pt = b >> 2, ms = b & 3;
    const int p0 = pt * 8;
    const int p  = p0 + (t >> 5);
    const int m0 = ms * 256 + (t & 31) * 8;
    if (p0 < 256) {
      *(float4*)&tile[t * 4] = *(const float4*)(kf + p0 * 128 + t * 4);
      __syncthreads();
      const float* kp = &tile[(t >> 5) * 128];
      for (int d = 0; d < 128; d += 4) {
        float4 kv = *(const float4*)&kp[d];
        float4 qa0 = *(const float4*)(Wq + (d + 0) * 1024 + m0);
        float4 qb0 = *(const float4*)(Wq + (d + 0) * 1024 + m0 + 4);
        float4 qa1 = *(const float4*)(Wq + (d + 1) * 1024 + m0);
        float4 qb1 = *(const float4*)(Wq + (d + 1) * 1024 + m0 + 4);
        float4 qa2 = *(const float4*)(Wq + (d + 2) * 1024 + m0);
        float4 qb2 = *(const float4*)(Wq + (d + 2) * 1024 + m0 + 4);
        float4 qa3 = *(const float4*)(Wq + (d + 3) * 1024 + m0);
        float4 qb3 = *(const float4*)(Wq + (d + 3) * 1024 + m0 + 4);
        acc[0] += kv.x*qa0.x + kv.y*qa1.x + kv.z*qa2.x + kv.w*qa3.x;
        acc[1] += kv.x*qa0.y + kv.y*qa1.y + kv.z*qa2.y + kv.w*qa3.y;
        acc[2] += kv.x*qa0.z + kv.y*qa1.z + kv.z*qa2.z + kv.w*qa3.z;
        acc[3] += kv.x*qa0.w + kv.y*qa1.w + kv.z*qa2.w + kv.w*qa3.w;
        acc[4] += kv.x*qb0.x + kv.y*qb1.x + kv.z*qb2.x + kv.w*qb3.x;
        acc[5] += kv.x*qb0.y + kv.y*qb1.y + kv.z*qb2.y + kv.w*qb3.y;
        acc[6] += kv.x*qb0.z + kv.y*qb1.z + kv.z*qb2.z + kv.w*qb3.z;
        acc[7] += kv.x*qb0.w + kv.y*qb1.w + kv.z*qb2.w + kv.w*qb3.w;
      }
    } else if (p == 256) {
      #pragma unroll
      for (int j = 0; j < 8; ++j) acc[j] = gate_w[m0 + j];
    }
    const int c = m0 >> 7, ct = p >> 4, k4 = (m0 >> 5) & 3;
    const int row = ((m0 >> 3) & 3) * 16 + (p & 15);
    ushort8 u;
    #pragma unroll
    for (int j = 0; j < 8; ++j) u[j] = f2bf(acc[j]);
    *(ushort8*)&ws[KWQ_OFF + ((size_t)(c * 17 + ct) * 4 + k4) * 512 + (size_t)row * 8] = u;
  } else {
    const int mb  = b - 136;
    const int m0t = mb * 8;
    const int m   = m0t + (t >> 5);
    const int p8  = (t & 31) * 8;
    *(float4*)&tile[t * 4] = *(const float4*)(Wo + (size_t)m0t * 128 + t * 4);
    __syncthreads();
    const float* wo = &tile[(t >> 5) * 128];
    for (int d = 0; d < 128; d += 4) {
      float4 wv = *(const float4*)&wo[d];
      float4 va0 = *(const float4*)(vT + (d + 0) * 256 + p8);
      float4 vb0 = *(const float4*)(vT + (d + 0) * 256 + p8 + 4);
      float4 va1 = *(const float4*)(vT + (d + 1) * 256 + p8);
      float4 vb1 = *(const float4*)(vT + (d + 1) * 256 + p8 + 4);
      float4 va2 = *(const float4*)(vT + (d + 2) * 256 + p8);
      float4 vb2 = *(const float4*)(vT + (d + 2) * 256 + p8 + 4);
      float4 va3 = *(const float4*)(vT + (d + 3) * 256 + p8);
      float4 vb3 = *(const float4*)(vT + (d + 3) * 256 + p8 + 4);
      acc[0] += wv.x*va0.x + wv.y*va1.x + wv.z*va2.x + wv.w*va3.x;
      acc[1] += wv.x*va0.y + wv.y*va1.y + wv.z*va2.y + wv.w*va3.y;
      acc[2] += wv.x*va0.z + wv.y*va1.z + wv.z*va2.z + wv.w*va3.z;
      acc[3] += wv.x*va0.w + wv.y*va1.w + wv.z*va2.w + wv.w*va3.w;
      acc[4] += wv.x*vb0.x + wv.y*vb1.x + wv.z*vb2.x + wv.w*vb3.x;
      acc[5] += wv.x*vb0.y + wv.y*vb1.y + wv.z*vb2.y + wv.w*vb3.y;
      acc[6] += wv.x*vb0.z + wv.y*vb1.z + wv.z*vb2.z + wv.w*vb3.z;
      acc[7] += wv.x*vb0.w + wv.y*vb1.w + wv.z*vb2.w + wv.w*vb3.w;
    }
    const int ctg = m >> 4, k8 = p8 >> 5;
    const int row = ((p8 >> 3) & 3) * 16 + (m & 15);
    ushort8 u;
    #pragma unroll
    for (int j = 0; j < 8; ++j) u[j] = f2bf(acc[j]);
    *(ushort8*)&ws[VWO_OFF + ((size_t)(ctg * 8 + k8) * 512) + (size_t)row * 8] = u;
  }
}

// ---------------------------------------------------------------------------
// fused: EXACT round-1 structure (measured 125us fused, VGPR=60, LDS=18.9KB)
//   with ONE change: __launch_bounds__(256, 8) -> 8 blocks/CU (LDS 151.5/160KB)
//   = 32 waves/CU, the hardware max, to hide the exposed global-load latency
//   that kept all pipes <15% busy at 13 waves/CU.
// ---------------------------------------------------------------------------
#define LDX 136        // x-tile row stride, ushorts (128 + 8 pad)
#define LDSLAB 264     // attn slab row stride, ushorts (256 + 8 pad)

__global__ __launch_bounds__(256, 8) void fused_kernel(
    const float* __restrict__ x, const float* __restrict__ gate_b,
    const ushort_t* __restrict__ ws, float* __restrict__ out)
{
  __shared__ __align__(16) char smem[2 * 32 * LDX * 2 + 32 * 4 * 4 * 2 + 32 * 4];
  ushort_t* xt0      = (ushort_t*)smem;                       // [32][136]
  ushort_t* xt1      = xt0 + 32 * LDX;
  ushort_t* slab     = (ushort_t*)smem;                       // [32][264] (attn phase)
  float*    pmax     = (float*)(smem + 2 * 32 * LDX * 2);     // [32][4]
  float*    psum     = pmax + 128;                            // [32][4]
  float*    gate_lds = psum + 128;                            // [32]

  const int t = threadIdx.x, wid = t >> 6, lane = t & 63;
  const int quad = lane >> 4, l16 = lane & 15;
  const int tok0 = blockIdx.x * 32;

  f32x4 acc[2][5];
  #pragma unroll
  for (int rt = 0; rt < 2; ++rt)
    #pragma unroll
    for (int ctl = 0; ctl < 5; ++ctl) acc[rt][ctl] = (f32x4){0.f,0.f,0.f,0.f};

  // ---------------- scores GEMM: 8 chunks of BK=128, dbuf staging ----------
  #pragma unroll
  for (int i = 0; i < 4; ++i) {
    int flat = i * 1024 + t * 4;
    int row = flat >> 7, col = flat & 127;
    float4 fv = *(const float4*)(x + (size_t)(tok0 + row) * 1024 + col);
    unsigned int pk0 = pack2bf(fv.x, fv.y), pk1 = pack2bf(fv.z, fv.w);
    *(unsigned long long*)&xt0[row * LDX + col] =
        (unsigned long long)pk0 | ((unsigned long long)pk1 << 32);
  }
  __syncthreads();

  for (int c = 0; c < 8; ++c) {
    ushort_t* cur = (c & 1) ? xt1 : xt0;
    ushort_t* nxt = (c & 1) ? xt0 : xt1;
    float4 fv[4];
    if (c < 7) {           // issue next chunk's global loads early
      #pragma unroll
      for (int i = 0; i < 4; ++i) {
        int flat = i * 1024 + t * 4;
        int row = flat >> 7, col = flat & 127;
        fv[i] = *(const float4*)(x + (size_t)(tok0 + row) * 1024 + (c + 1) * 128 + col);
      }
    }
    #pragma unroll
    for (int k4 = 0; k4 < 4; ++k4) {
      short8 a[2];
      #pragma unroll
      for (int rt = 0; rt < 2; ++rt)
        a[rt] = *(const short8*)&cur[(rt * 16 + l16) * LDX + k4 * 32 + quad * 8];
      #pragma unroll
      for (int ctl = 0; ctl < 5; ++ctl) {
        if (ctl == 4 && wid != 3) continue;     // wave-uniform branch
        const int ct = wid * 4 + ctl;
        short8 bfr = *(const short8*)&ws[KWQ_OFF +
            ((size_t)(c * 17 + ct) * 4 + k4) * 512 + (size_t)lane * 8];
        #pragma unroll
        for (int rt = 0; rt < 2; ++rt) acc[rt][ctl] = MFMA16(a[rt], bfr, acc[rt][ctl]);
      }
    }
    if (c < 7) {           // pack + write next buffer, single barrier per chunk
      #pragma unroll
      for (int i = 0; i < 4; ++i) {
        int flat = i * 1024 + t * 4;
        int row = flat >> 7, col = flat & 127;
        unsigned int pk0 = pack2bf(fv[i].x, fv[i].y), pk1 = pack2bf(fv[i].z, fv[i].w);
        *(unsigned long long*)&nxt[row * LDX + col] =
            (unsigned long long)pk0 | ((unsigned long long)pk1 << 32);
      }
      __syncthreads();
    }
  }

  // ---------------- cross-wave softmax --------------------------------------
  const float SC = 0.08838834764831845f * 1.44269504088896f;  // 1/sqrt(128) * log2e
  #pragma unroll
  for (int rt = 0; rt < 2; ++rt)
    #pragma unroll
    for (int r = 0; r < 4; ++r) {
      float m = acc[rt][0][r];
      #pragma unroll
      for (int ctl = 1; ctl < 4; ++ctl) m = fmaxf(m, acc[rt][ctl][r]);
      #pragma unroll
      for (int msk = 1; msk < 16; msk <<= 1) m = fmaxf(m, __shfl_xor(m, msk, 64));
      if (l16 == 0) pmax[(rt * 16 + quad * 4 + r) * 4 + wid] = m;
    }
  __syncthreads();   // barrier: pmax complete (also closes last xt reads)
  float Mf[2][4];
  #pragma unroll
  for (int rt = 0; rt < 2; ++rt)
    #pragma unroll
    for (int r = 0; r < 4; ++r) {
      f32x4 pm = *(f32x4*)&pmax[(rt * 16 + quad * 4 + r) * 4];
      Mf[rt][r] = fmaxf(fmaxf(pm[0], pm[1]), fmaxf(pm[2], pm[3]));
    }
  float Sm[2][4];
  #pragma unroll
  for (int rt = 0; rt < 2; ++rt)
    #pragma unroll
    for (int r = 0; r < 4; ++r) Sm[rt][r] = 0.f;
  #pragma unroll
  for (int rt = 0; rt < 2; ++rt)
    #pragma unroll
    for (int ctl = 0; ctl < 4; ++ctl)
      #pragma unroll
      for (int r = 0; r < 4; ++r) {
        float e = exp2f((acc[rt][ctl][r] - Mf[rt][r]) * SC);
        acc[rt][ctl][r] = e;
        Sm[rt][r] += e;
      }
  #pragma unroll
  for (int rt = 0; rt < 2; ++rt)
    #pragma unroll
    for (int r = 0; r < 4; ++r) {
      #pragma unroll
      for (int msk = 1; msk < 16; msk <<= 1) Sm[rt][r] += __shfl_xor(Sm[rt][r], msk, 64);
    }
  if (l16 == 0) {
    #pragma unroll
    for (int rt = 0; rt < 2; ++rt)
      #pragma unroll
      for (int r = 0; r < 4; ++r)
        psum[(rt * 16 + quad * 4 + r) * 4 + wid] = Sm[rt][r];
    if (wid == 3) {
      float gb = gate_b[0];
      #pragma unroll
      for (int rt = 0; rt < 2; ++rt)
        #pragma unroll
        for (int r = 0; r < 4; ++r) {
          float lg = acc[rt][4][r] + gb;   // raw score, col 256 (l16==0)
          gate_lds[rt * 16 + quad * 4 + r] = 1.f / (1.f + __expf(-lg));
        }
    }
  }
  __syncthreads();   // barrier: psum + gate complete
  float scl[2][4];   // gate / sum  (gate folded into attn slab)
  #pragma unroll
  for (int rt = 0; rt < 2; ++rt)
    #pragma unroll
    for (int r = 0; r < 4; ++r) {
      f32x4 ps = *(f32x4*)&psum[(rt * 16 + quad * 4 + r) * 4];
      float g = gate_lds[rt * 16 + quad * 4 + r];
      scl[rt][r] = g / (ps[0] + ps[1] + ps[2] + ps[3]);
    }

  // attn*gate -> shared slab (each wave writes its ct columns)
  #pragma unroll
  for (int rt = 0; rt < 2; ++rt)
    #pragma unroll
    for (int ctl = 0; ctl < 4; ++ctl)
      #pragma unroll
      for (int r = 0; r < 4; ++r)
        slab[(rt * 16 + quad * 4 + r) * LDSLAB + (wid * 4 + ctl) * 16 + l16] =
            f2bf(acc[rt][ctl][r] * scl[rt][r]);
  __syncthreads();   // barrier: slab complete

  // ---------------- out GEMM: slab @ VWo, wave w owns cols [w*256, +256) ----
  short8 af[2][8];
  #pragma unroll
  for (int rt = 0; rt < 2; ++rt)
    #pragma unroll
    for (int k8 = 0; k8 < 8; ++k8)
      af[rt][k8] = *(const short8*)&slab[(rt * 16 + l16) * LDSLAB + k8 * 32 + quad * 8];

  const int n0 = wid * 256;
  for (int nt = 0; nt < 16; ++nt) {
    const int ctg = (n0 >> 4) + nt;
    short8 bf[8];
    #pragma unroll
    for (int k8 = 0; k8 < 8; ++k8)
      bf[k8] = *(const short8*)&ws[VWO_OFF + ((size_t)(ctg * 8 + k8) * 512) + (size_t)lane * 8];
    f32x4 oa[2];
    #pragma unroll
    for (int rt = 0; rt < 2; ++rt) oa[rt] = (f32x4){0.f,0.f,0.f,0.f};
    #pragma unroll
    for (int rt = 0; rt < 2; ++rt)
      #pragma unroll
      for (int k8 = 0; k8 < 8; ++k8)
        oa[rt] = MFMA16(af[rt][k8], bf[k8], oa[rt]);
    #pragma unroll
    for (int rt = 0; rt < 2; ++rt)
      #pragma unroll
      for (int r = 0; r < 4; ++r)
        __builtin_nontemporal_store(oa[rt][r],
            &out[(size_t)(tok0 + rt * 16 + quad * 4 + r) * 1024 + n0 + nt * 16 + l16]);
  }
}

// ---------------------------------------------------------------------------
extern "C" void kernel_launch(void* const* d_in, const int* in_sizes, int n_in,
                              void* d_out, int out_size, void* d_ws, size_t ws_size,
                              hipStream_t stream) {
  const float* x    = (const float*)d_in[0];
  const float* prim = (const float*)d_in[1];
  const float* Wq   = (const float*)d_in[2];
  const float* Wk   = (const float*)d_in[3];
  const float* Wv   = (const float*)d_in[4];
  const float* Wo   = (const float*)d_in[5];
  const float* gw   = (const float*)d_in[6];
  const float* gb   = (const float*)d_in[7];
  float* out = (float*)d_out;
  ushort_t* ws = (ushort_t*)d_ws;

  prep1_kernel<<<256, 256, 0, stream>>>(prim, Wk, Wv, ws);
  prep2_kernel<<<264, 256, 0, stream>>>(Wq, Wo, gw, ws);
  fused_kernel<<<1024, 256, 0, stream>>>(x, gb, ws, out);
}

// Round 6
// 382.202 us; speedup vs baseline: 1.3625x; 1.3625x over previous
//
#include <hip/hip_runtime.h>
#include <hip/hip_bf16.h>

typedef unsigned short ushort_t;
typedef __attribute__((ext_vector_type(8))) short short8;
typedef __attribute__((ext_vector_type(8))) unsigned short ushort8;
typedef __attribute__((ext_vector_type(4))) float f32x4;
typedef __attribute__((ext_vector_type(4))) unsigned int u32x4;

#define MFMA16(a,b,c) __builtin_amdgcn_mfma_f32_16x16x32_bf16((a),(b),(c),0,0,0)

__device__ __forceinline__ ushort_t f2bf(float f) {
  unsigned int u = __builtin_bit_cast(unsigned int, f);
  u += 0x7FFFu + ((u >> 16) & 1u);
  return (ushort_t)(u >> 16);
}
__device__ __forceinline__ unsigned int pack2bf(float a, float b) {
  unsigned int ua = __builtin_bit_cast(unsigned int, a);
  unsigned int ub = __builtin_bit_cast(unsigned int, b);
  ua += 0x7FFFu + ((ua >> 16) & 1u);
  ub += 0x7FFFu + ((ub >> 16) & 1u);
  return (ua >> 16) | (ub & 0xFFFF0000u);
}
__device__ __forceinline__ short8 pack8(float4 lo, float4 hi) {
  u32x4 u;
  u.x = pack2bf(lo.x, lo.y); u.y = pack2bf(lo.z, lo.w);
  u.z = pack2bf(hi.x, hi.y); u.w = pack2bf(hi.z, hi.w);
  return __builtin_bit_cast(short8, u);
}

// Problem dims
#define DMd 1024
#define DPd 128
#define PPd 256

// Workspace layout (ushort element offsets unless noted)
// KWqExt fragments: [chunk 8][ct 17][k4 4][lane 64][8]  (272 x 1024 bf16)
#define KWQ_OFF 0
#define KWQ_SIZE (8*17*4*512)          // 278528
// VWo fragments: [ctg 64][k8 8][lane 64][8]             (256 x 1024 bf16)
#define VWO_OFF KWQ_SIZE
#define VWO_SIZE (64*8*512)            // 262144
#define KV_BYTE_OFF ((size_t)(KWQ_SIZE + VWO_SIZE) * 2)  // then: k [256][128] f32, vT [128][256] f32

// ---------------------------------------------------------------------------
// prep1: k = prim @ Wk^T (row-major [256][128]) and vT = (prim @ Wv^T)^T
// ---------------------------------------------------------------------------
__global__ __launch_bounds__(256) void prep1_kernel(
    const float* __restrict__ prim, const float* __restrict__ Wk,
    const float* __restrict__ Wv, ushort_t* __restrict__ ws) {
  __shared__ __align__(16) float Wl[128 * 132];
  __shared__ __align__(16) float pl[2 * 128];
  const int t = threadIdx.x;
  const int mat = blockIdx.x & 1;
  const int p0 = (blockIdx.x >> 1) * 2;
  const float* W = mat ? Wv : Wk;
  #pragma unroll
  for (int i = 0; i < 16; ++i) {
    int w = (i * 256 + t) * 4;
    int row = w >> 7, col = w & 127;
    *(float4*)&Wl[row * 132 + col] = *(const float4*)(W + w);
  }
  if (t < 64) {
    int row = t >> 5, col = (t & 31) * 4;
    *(float4*)&pl[row * 128 + col] = *(const float4*)(prim + (p0 + row) * 128 + col);
  }
  __syncthreads();
  const int d = t & 127, slot = t >> 7;
  float a0 = 0.f, a1 = 0.f, a2 = 0.f, a3 = 0.f;
  #pragma unroll
  for (int j = 0; j < 128; j += 4) {
    float4 w4 = *(const float4*)&Wl[d * 132 + j];
    float4 p4 = *(const float4*)&pl[slot * 128 + j];
    a0 += w4.x * p4.x; a1 += w4.y * p4.y; a2 += w4.z * p4.z; a3 += w4.w * p4.w;
  }
  float r = (a0 + a1) + (a2 + a3);
  float* kf = (float*)((char*)ws + KV_BYTE_OFF);
  float* vT = kf + 32768;
  if (mat == 0) kf[(p0 + slot) * 128 + d] = r;
  else          vT[d * 256 + p0 + slot] = r;
}

// ---------------------------------------------------------------------------
// prep2: 264 blocks; emits frag-major KWqExt / VWo.
// ---------------------------------------------------------------------------
__global__ __launch_bounds__(256) void prep2_kernel(
    const float* __restrict__ Wq, const float* __restrict__ Wo,
    const float* __restrict__ gate_w, ushort_t* __restrict__ ws) {
  const float* kf = (const float*)((const char*)ws + KV_BYTE_OFF);
  const float* vT = kf + 32768;
  __shared__ __align__(16) float tile[8 * 128];
  const int b = blockIdx.x, t = threadIdx.x;
  float acc[8];
  #pragma unroll
  for (int j = 0; j < 8; ++j) acc[j] = 0.f;
  if (b < 136) {
    const int pt = b >> 2, ms = b & 3;
    const int p0 = pt * 8;
    const int p  = p0 + (t >> 5);
    const int m0 = ms * 256 + (t & 31) * 8;
    if (p0 < 256) {
      *(float4*)&tile[t * 4] = *(const float4*)(kf + p0 * 128 + t * 4);
      __syncthreads();
      const float* kp = &tile[(t >> 5) * 128];
      for (int d = 0; d < 128; d += 4) {
        float4 kv = *(const float4*)&kp[d];
        float4 qa0 = *(const float4*)(Wq + (d + 0) * 1024 + m0);
        float4 qb0 = *(const float4*)(Wq + (d + 0) * 1024 + m0 + 4);
        float4 qa1 = *(const float4*)(Wq + (d + 1) * 1024 + m0);
        float4 qb1 = *(const float4*)(Wq + (d + 1) * 1024 + m0 + 4);
        float4 qa2 = *(const float4*)(Wq + (d + 2) * 1024 + m0);
        float4 qb2 = *(const float4*)(Wq + (d + 2) * 1024 + m0 + 4);
        float4 qa3 = *(const float4*)(Wq + (d + 3) * 1024 + m0);
        float4 qb3 = *(const float4*)(Wq + (d + 3) * 1024 + m0 + 4);
        acc[0] += kv.x*qa0.x + kv.y*qa1.x + kv.z*qa2.x + kv.w*qa3.x;
        acc[1] += kv.x*qa0.y + kv.y*qa1.y + kv.z*qa2.y + kv.w*qa3.y;
        acc[2] += kv.x*qa0.z + kv.y*qa1.z + kv.z*qa2.z + kv.w*qa3.z;
        acc[3] += kv.x*qa0.w + kv.y*qa1.w + kv.z*qa2.w + kv.w*qa3.w;
        acc[4] += kv.x*qb0.x + kv.y*qb1.x + kv.z*qb2.x + kv.w*qb3.x;
        acc[5] += kv.x*qb0.y + kv.y*qb1.y + kv.z*qb2.y + kv.w*qb3.y;
        acc[6] += kv.x*qb0.z + kv.y*qb1.z + kv.z*qb2.z + kv.w*qb3.z;
        acc[7] += kv.x*qb0.w + kv.y*qb1.w + kv.z*qb2.w + kv.w*qb3.w;
      }
    } else if (p == 256) {
      #pragma unroll
      for (int j = 0; j < 8; ++j) acc[j] = gate_w[m0 + j];
    }
    const int c = m0 >> 7, ct = p >> 4, k4 = (m0 >> 5) & 3;
    const int row = ((m0 >> 3) & 3) * 16 + (p & 15);
    ushort8 u;
    #pragma unroll
    for (int j = 0; j < 8; ++j) u[j] = f2bf(acc[j]);
    *(ushort8*)&ws[KWQ_OFF + ((size_t)(c * 17 + ct) * 4 + k4) * 512 + (size_t)row * 8] = u;
  } else {
    const int mb  = b - 136;
    const int m0t = mb * 8;
    const int m   = m0t + (t >> 5);
    const int p8  = (t & 31) * 8;
    *(float4*)&tile[t * 4] = *(const float4*)(Wo + (size_t)m0t * 128 + t * 4);
    __syncthreads();
    const float* wo = &tile[(t >> 5) * 128];
    for (int d = 0; d < 128; d += 4) {
      float4 wv = *(const float4*)&wo[d];
      float4 va0 = *(const float4*)(vT + (d + 0) * 256 + p8);
      float4 vb0 = *(const float4*)(vT + (d + 0) * 256 + p8 + 4);
      float4 va1 = *(const float4*)(vT + (d + 1) * 256 + p8);
      float4 vb1 = *(const float4*)(vT + (d + 1) * 256 + p8 + 4);
      float4 va2 = *(const float4*)(vT + (d + 2) * 256 + p8);
      float4 vb2 = *(const float4*)(vT + (d + 2) * 256 + p8 + 4);
      float4 va3 = *(const float4*)(vT + (d + 3) * 256 + p8);
      float4 vb3 = *(const float4*)(vT + (d + 3) * 256 + p8 + 4);
      acc[0] += wv.x*va0.x + wv.y*va1.x + wv.z*va2.x + wv.w*va3.x;
      acc[1] += wv.x*va0.y + wv.y*va1.y + wv.z*va2.y + wv.w*va3.y;
      acc[2] += wv.x*va0.z + wv.y*va1.z + wv.z*va2.z + wv.w*va3.z;
      acc[3] += wv.x*va0.w + wv.y*va1.w + wv.z*va2.w + wv.w*va3.w;
      acc[4] += wv.x*vb0.x + wv.y*vb1.x + wv.z*vb2.x + wv.w*vb3.x;
      acc[5] += wv.x*vb0.y + wv.y*vb1.y + wv.z*vb2.y + wv.w*vb3.y;
      acc[6] += wv.x*vb0.z + wv.y*vb1.z + wv.z*vb2.z + wv.w*vb3.z;
      acc[7] += wv.x*vb0.w + wv.y*vb1.w + wv.z*vb2.w + wv.w*vb3.w;
    }
    const int ctg = m >> 4, k8 = p8 >> 5;
    const int row = ((p8 >> 3) & 3) * 16 + (m & 15);
    ushort8 u;
    #pragma unroll
    for (int j = 0; j < 8; ++j) u[j] = f2bf(acc[j]);
    *(ushort8*)&ws[VWO_OFF + ((size_t)(ctg * 8 + k8) * 512) + (size_t)row * 8] = u;
  }
}

// ---------------------------------------------------------------------------
// fused: round-4 structure (barrier/branch-free scores loop, direct global
//   A-loads, batched B-loads, static-index dbuf out GEMM) with the ONE change
//   __launch_bounds__(256, 3): combined VGPR+AGPR cap 170 (vs 128 at min=4),
//   which fits the structure's ~140-150-reg natural demand WITHOUT the
//   scratch spills that produced round-4's 430 MB of extra HBM traffic
//   (VGPR_Count=32/64 rounds confirmed: rocprof VGPR excludes AGPR; budget
//   is VGPR+AGPR <= 512/waves_per_simd).
// ---------------------------------------------------------------------------
#define LDSLAB 264     // attn slab row stride, ushorts (256 + 8 pad)

__global__ __launch_bounds__(256, 3) void fused_kernel(
    const float* __restrict__ x, const float* __restrict__ gate_b,
    const ushort_t* __restrict__ ws, float* __restrict__ out)
{
  __shared__ __align__(16) char smem[32 * LDSLAB * 2 + 32 * 4 * 4 * 2 + 32 * 4];
  ushort_t* slab     = (ushort_t*)smem;                       // [32][264]
  float*    pmax     = (float*)(smem + 32 * LDSLAB * 2);      // [32][4]
  float*    psum     = pmax + 128;                            // [32][4]
  float*    gate_lds = psum + 128;                            // [32]

  const int t = threadIdx.x, wid = t >> 6, lane = t & 63;
  const int quad = lane >> 4, l16 = lane & 15;
  const int tok0 = blockIdx.x * 32;
  const int ct0 = wid * 4;

  f32x4 acc[2][5];
  #pragma unroll
  for (int rt = 0; rt < 2; ++rt)
    #pragma unroll
    for (int ctl = 0; ctl < 5; ++ctl) acc[rt][ctl] = (f32x4){0.f,0.f,0.f,0.f};

  // ---------------- scores GEMM: 8 chunks of BK=128, barrier/branch-free ----
  const float* xr0 = x + (size_t)(tok0 + l16) * 1024 + quad * 8;        // rt=0 row
  const float* xr1 = xr0 + 16 * 1024;                                    // rt=1 row
  for (int c = 0; c < 8; ++c) {
    const ushort_t* wb = ws + KWQ_OFF + (size_t)(c * 17) * 4 * 512 + (size_t)lane * 8;
    const float* px0 = xr0 + c * 128;
    const float* px1 = xr1 + c * 128;
    #pragma unroll
    for (int k4 = 0; k4 < 4; ++k4) {
      // batched loads: 4 x-vec loads + 5 B-fragment loads, then 10 MFMAs
      float4 fa0 = *(const float4*)(px0 + k4 * 32);
      float4 fa1 = *(const float4*)(px0 + k4 * 32 + 4);
      float4 fb0 = *(const float4*)(px1 + k4 * 32);
      float4 fb1 = *(const float4*)(px1 + k4 * 32 + 4);
      short8 b0 = *(const short8*)&wb[(size_t)((ct0 + 0) * 4 + k4) * 512];
      short8 b1 = *(const short8*)&wb[(size_t)((ct0 + 1) * 4 + k4) * 512];
      short8 b2 = *(const short8*)&wb[(size_t)((ct0 + 2) * 4 + k4) * 512];
      short8 b3 = *(const short8*)&wb[(size_t)((ct0 + 3) * 4 + k4) * 512];
      short8 b4 = *(const short8*)&wb[(size_t)((ct0 + 4) * 4 + k4) * 512];
      short8 a0 = pack8(fa0, fa1);
      short8 a1 = pack8(fb0, fb1);
      acc[0][0] = MFMA16(a0, b0, acc[0][0]);
      acc[1][0] = MFMA16(a1, b0, acc[1][0]);
      acc[0][1] = MFMA16(a0, b1, acc[0][1]);
      acc[1][1] = MFMA16(a1, b1, acc[1][1]);
      acc[0][2] = MFMA16(a0, b2, acc[0][2]);
      acc[1][2] = MFMA16(a1, b2, acc[1][2]);
      acc[0][3] = MFMA16(a0, b3, acc[0][3]);
      acc[1][3] = MFMA16(a1, b3, acc[1][3]);
      acc[0][4] = MFMA16(a0, b4, acc[0][4]);
      acc[1][4] = MFMA16(a1, b4, acc[1][4]);
    }
  }

  // ---------------- cross-wave softmax --------------------------------------
  const float SC = 0.08838834764831845f * 1.44269504088896f;  // 1/sqrt(128) * log2e
  #pragma unroll
  for (int rt = 0; rt < 2; ++rt)
    #pragma unroll
    for (int r = 0; r < 4; ++r) {
      float m = acc[rt][0][r];
      #pragma unroll
      for (int ctl = 1; ctl < 4; ++ctl) m = fmaxf(m, acc[rt][ctl][r]);
      #pragma unroll
      for (int msk = 1; msk < 16; msk <<= 1) m = fmaxf(m, __shfl_xor(m, msk, 64));
      if (l16 == 0) pmax[(rt * 16 + quad * 4 + r) * 4 + wid] = m;
    }
  __syncthreads();   // pmax complete
  float Mf[2][4];
  #pragma unroll
  for (int rt = 0; rt < 2; ++rt)
    #pragma unroll
    for (int r = 0; r < 4; ++r) {
      f32x4 pm = *(f32x4*)&pmax[(rt * 16 + quad * 4 + r) * 4];
      Mf[rt][r] = fmaxf(fmaxf(pm[0], pm[1]), fmaxf(pm[2], pm[3]));
    }
  float Sm[2][4];
  #pragma unroll
  for (int rt = 0; rt < 2; ++rt)
    #pragma unroll
    for (int r = 0; r < 4; ++r) Sm[rt][r] = 0.f;
  #pragma unroll
  for (int rt = 0; rt < 2; ++rt)
    #pragma unroll
    for (int ctl = 0; ctl < 4; ++ctl)
      #pragma unroll
      for (int r = 0; r < 4; ++r) {
        float e = exp2f((acc[rt][ctl][r] - Mf[rt][r]) * SC);
        acc[rt][ctl][r] = e;
        Sm[rt][r] += e;
      }
  #pragma unroll
  for (int rt = 0; rt < 2; ++rt)
    #pragma unroll
    for (int r = 0; r < 4; ++r) {
      #pragma unroll
      for (int msk = 1; msk < 16; msk <<= 1) Sm[rt][r] += __shfl_xor(Sm[rt][r], msk, 64);
    }
  if (l16 == 0) {
    #pragma unroll
    for (int rt = 0; rt < 2; ++rt)
      #pragma unroll
      for (int r = 0; r < 4; ++r)
        psum[(rt * 16 + quad * 4 + r) * 4 + wid] = Sm[rt][r];
    if (wid == 3) {
      float gb = gate_b[0];
      #pragma unroll
      for (int rt = 0; rt < 2; ++rt)
        #pragma unroll
        for (int r = 0; r < 4; ++r) {
          float lg = acc[rt][4][r] + gb;   // raw score, col 256 (l16==0)
          gate_lds[rt * 16 + quad * 4 + r] = 1.f / (1.f + __expf(-lg));
        }
    }
  }
  __syncthreads();   // psum + gate complete
  float scl[2][4];   // gate / sum (gate folded into slab)
  #pragma unroll
  for (int rt = 0; rt < 2; ++rt)
    #pragma unroll
    for (int r = 0; r < 4; ++r) {
      f32x4 ps = *(f32x4*)&psum[(rt * 16 + quad * 4 + r) * 4];
      float g = gate_lds[rt * 16 + quad * 4 + r];
      scl[rt][r] = g / (ps[0] + ps[1] + ps[2] + ps[3]);
    }

  // attn*gate -> shared slab (each wave writes its 4 ct columns)
  #pragma unroll
  for (int rt = 0; rt < 2; ++rt)
    #pragma unroll
    for (int ctl = 0; ctl < 4; ++ctl)
      #pragma unroll
      for (int r = 0; r < 4; ++r)
        slab[(rt * 16 + quad * 4 + r) * LDSLAB + (ct0 + ctl) * 16 + l16] =
            f2bf(acc[rt][ctl][r] * scl[rt][r]);
  __syncthreads();   // slab complete

  // ---------------- out GEMM: slab @ VWo, wave w owns cols [w*256, +256) ----
  short8 af[2][8];
  #pragma unroll
  for (int rt = 0; rt < 2; ++rt)
    #pragma unroll
    for (int k8 = 0; k8 < 8; ++k8)
      af[rt][k8] = *(const short8*)&slab[(rt * 16 + l16) * LDSLAB + k8 * 32 + quad * 8];

  const int n0 = wid * 256;
  const ushort_t* vb = ws + VWO_OFF + (size_t)(n0 >> 4) * (8 * 512) + (size_t)lane * 8;

  short8 bfA[8], bfB[8];
  #pragma unroll
  for (int k8 = 0; k8 < 8; ++k8)
    bfA[k8] = *(const short8*)&vb[(size_t)k8 * 512];

  #pragma unroll 2
  for (int ntp = 0; ntp < 8; ++ntp) {
    const int ntA = ntp * 2, ntB = ntA + 1;
    // prefetch ntB while computing ntA (named arrays, static indices only)
    #pragma unroll
    for (int k8 = 0; k8 < 8; ++k8)
      bfB[k8] = *(const short8*)&vb[(size_t)(ntB * 8 + k8) * 512];
    {
      f32x4 oa[2];
      #pragma unroll
      for (int rt = 0; rt < 2; ++rt) oa[rt] = (f32x4){0.f,0.f,0.f,0.f};
      #pragma unroll
      for (int rt = 0; rt < 2; ++rt)
        #pragma unroll
        for (int k8 = 0; k8 < 8; ++k8)
          oa[rt] = MFMA16(af[rt][k8], bfA[k8], oa[rt]);
      #pragma unroll
      for (int rt = 0; rt < 2; ++rt)
        #pragma unroll
        for (int r = 0; r < 4; ++r)
          __builtin_nontemporal_store(oa[rt][r],
              &out[(size_t)(tok0 + rt * 16 + quad * 4 + r) * 1024 + n0 + ntA * 16 + l16]);
    }
    if (ntp < 7) {
      #pragma unroll
      for (int k8 = 0; k8 < 8; ++k8)
        bfA[k8] = *(const short8*)&vb[(size_t)((ntA + 2) * 8 + k8) * 512];
    }
    {
      f32x4 oa[2];
      #pragma unroll
      for (int rt = 0; rt < 2; ++rt) oa[rt] = (f32x4){0.f,0.f,0.f,0.f};
      #pragma unroll
      for (int rt = 0; rt < 2; ++rt)
        #pragma unroll
        for (int k8 = 0; k8 < 8; ++k8)
          oa[rt] = MFMA16(af[rt][k8], bfB[k8], oa[rt]);
      #pragma unroll
      for (int rt = 0; rt < 2; ++rt)
        #pragma unroll
        for (int r = 0; r < 4; ++r)
          __builtin_nontemporal_store(oa[rt][r],
              &out[(size_t)(tok0 + rt * 16 + quad * 4 + r) * 1024 + n0 + ntB * 16 + l16]);
    }
  }
}

// ---------------------------------------------------------------------------
extern "C" void kernel_launch(void* const* d_in, const int* in_sizes, int n_in,
                              void* d_out, int out_size, void* d_ws, size_t ws_size,
                              hipStream_t stream) {
  const float* x    = (const float*)d_in[0];
  const float* prim = (const float*)d_in[1];
  const float* Wq   = (const float*)d_in[2];
  const float* Wk   = (const float*)d_in[3];
  const float* Wv   = (const float*)d_in[4];
  const float* Wo   = (const float*)d_in[5];
  const float* gw   = (const float*)d_in[6];
  const float* gb   = (const float*)d_in[7];
  float* out = (float*)d_out;
  ushort_t* ws = (ushort_t*)d_ws;

  prep1_kernel<<<256, 256, 0, stream>>>(prim, Wk, Wv, ws);
  prep2_kernel<<<264, 256, 0, stream>>>(Wq, Wo, gw, ws);
  fused_kernel<<<1024, 256, 0, stream>>>(x, gb, ws, out);
}

// Round 7
// 327.781 us; speedup vs baseline: 1.5887x; 1.1660x over previous
//
#include <hip/hip_runtime.h>
#include <hip/hip_bf16.h>

typedef unsigned short ushort_t;
typedef __attribute__((ext_vector_type(8))) short short8;
typedef __attribute__((ext_vector_type(8))) unsigned short ushort8;
typedef __attribute__((ext_vector_type(4))) float f32x4;

#define MFMA16(a,b,c) __builtin_amdgcn_mfma_f32_16x16x32_bf16((a),(b),(c),0,0,0)

__device__ __forceinline__ ushort_t f2bf(float f) {
  unsigned int u = __builtin_bit_cast(unsigned int, f);
  u += 0x7FFFu + ((u >> 16) & 1u);
  return (ushort_t)(u >> 16);
}
__device__ __forceinline__ unsigned int pack2bf(float a, float b) {
  unsigned int ua = __builtin_bit_cast(unsigned int, a);
  unsigned int ub = __builtin_bit_cast(unsigned int, b);
  ua += 0x7FFFu + ((ua >> 16) & 1u);
  ub += 0x7FFFu + ((ub >> 16) & 1u);
  return (ua >> 16) | (ub & 0xFFFF0000u);
}

// Problem dims
#define DMd 1024
#define DPd 128
#define PPd 256

// Workspace layout (ushort element offsets unless noted)
// KWqExt fragments: [chunk 8][ct 17][k4 4][lane 64][8]  (272 x 1024 bf16)
#define KWQ_OFF 0
#define KWQ_SIZE (8*17*4*512)          // 278528
// VWo fragments: [ctg 64][k8 8][lane 64][8]             (256 x 1024 bf16)
#define VWO_OFF KWQ_SIZE
#define VWO_SIZE (64*8*512)            // 262144
#define KV_BYTE_OFF ((size_t)(KWQ_SIZE + VWO_SIZE) * 2)  // then: k [256][128] f32, vT [128][256] f32

// ---------------------------------------------------------------------------
// prep1: k = prim @ Wk^T (row-major [256][128]) and vT = (prim @ Wv^T)^T
// ---------------------------------------------------------------------------
__global__ __launch_bounds__(256) void prep1_kernel(
    const float* __restrict__ prim, const float* __restrict__ Wk,
    const float* __restrict__ Wv, ushort_t* __restrict__ ws) {
  __shared__ __align__(16) float Wl[128 * 132];
  __shared__ __align__(16) float pl[2 * 128];
  const int t = threadIdx.x;
  const int mat = blockIdx.x & 1;
  const int p0 = (blockIdx.x >> 1) * 2;
  const float* W = mat ? Wv : Wk;
  #pragma unroll
  for (int i = 0; i < 16; ++i) {
    int w = (i * 256 + t) * 4;
    int row = w >> 7, col = w & 127;
    *(float4*)&Wl[row * 132 + col] = *(const float4*)(W + w);
  }
  if (t < 64) {
    int row = t >> 5, col = (t & 31) * 4;
    *(float4*)&pl[row * 128 + col] = *(const float4*)(prim + (p0 + row) * 128 + col);
  }
  __syncthreads();
  const int d = t & 127, slot = t >> 7;
  float a0 = 0.f, a1 = 0.f, a2 = 0.f, a3 = 0.f;
  #pragma unroll
  for (int j = 0; j < 128; j += 4) {
    float4 w4 = *(const float4*)&Wl[d * 132 + j];
    float4 p4 = *(const float4*)&pl[slot * 128 + j];
    a0 += w4.x * p4.x; a1 += w4.y * p4.y; a2 += w4.z * p4.z; a3 += w4.w * p4.w;
  }
  float r = (a0 + a1) + (a2 + a3);
  float* kf = (float*)((char*)ws + KV_BYTE_OFF);
  float* vT = kf + 32768;
  if (mat == 0) kf[(p0 + slot) * 128 + d] = r;
  else          vT[d * 256 + p0 + slot] = r;
}

// ---------------------------------------------------------------------------
// prep2: 264 blocks; emits frag-major KWqExt / VWo.
// ---------------------------------------------------------------------------
__global__ __launch_bounds__(256) void prep2_kernel(
    const float* __restrict__ Wq, const float* __restrict__ Wo,
    const float* __restrict__ gate_w, ushort_t* __restrict__ ws) {
  const float* kf = (const float*)((const char*)ws + KV_BYTE_OFF);
  const float* vT = kf + 32768;
  __shared__ __align__(16) float tile[8 * 128];
  const int b = blockIdx.x, t = threadIdx.x;
  float acc[8];
  #pragma unroll
  for (int j = 0; j < 8; ++j) acc[j] = 0.f;
  if (b < 136) {
    const int pt = b >> 2, ms = b & 3;
    const int p0 = pt * 8;
    const int p  = p0 + (t >> 5);
    const int m0 = ms * 256 + (t & 31) * 8;
    if (p0 < 256) {
      *(float4*)&tile[t * 4] = *(const float4*)(kf + p0 * 128 + t * 4);
      __syncthreads();
      const float* kp = &tile[(t >> 5) * 128];
      for (int d = 0; d < 128; d += 4) {
        float4 kv = *(const float4*)&kp[d];
        float4 qa0 = *(const float4*)(Wq + (d + 0) * 1024 + m0);
        float4 qb0 = *(const float4*)(Wq + (d + 0) * 1024 + m0 + 4);
        float4 qa1 = *(const float4*)(Wq + (d + 1) * 1024 + m0);
        float4 qb1 = *(const float4*)(Wq + (d + 1) * 1024 + m0 + 4);
        float4 qa2 = *(const float4*)(Wq + (d + 2) * 1024 + m0);
        float4 qb2 = *(const float4*)(Wq + (d + 2) * 1024 + m0 + 4);
        float4 qa3 = *(const float4*)(Wq + (d + 3) * 1024 + m0);
        float4 qb3 = *(const float4*)(Wq + (d + 3) * 1024 + m0 + 4);
        acc[0] += kv.x*qa0.x + kv.y*qa1.x + kv.z*qa2.x + kv.w*qa3.x;
        acc[1] += kv.x*qa0.y + kv.y*qa1.y + kv.z*qa2.y + kv.w*qa3.y;
        acc[2] += kv.x*qa0.z + kv.y*qa1.z + kv.z*qa2.z + kv.w*qa3.z;
        acc[3] += kv.x*qa0.w + kv.y*qa1.w + kv.z*qa2.w + kv.w*qa3.w;
        acc[4] += kv.x*qb0.x + kv.y*qb1.x + kv.z*qb2.x + kv.w*qb3.x;
        acc[5] += kv.x*qb0.y + kv.y*qb1.y + kv.z*qb2.y + kv.w*qb3.y;
        acc[6] += kv.x*qb0.z + kv.y*qb1.z + kv.z*qb2.z + kv.w*qb3.z;
        acc[7] += kv.x*qb0.w + kv.y*qb1.w + kv.z*qb2.w + kv.w*qb3.w;
      }
    } else if (p == 256) {
      #pragma unroll
      for (int j = 0; j < 8; ++j) acc[j] = gate_w[m0 + j];
    }
    const int c = m0 >> 7, ct = p >> 4, k4 = (m0 >> 5) & 3;
    const int row = ((m0 >> 3) & 3) * 16 + (p & 15);
    ushort8 u;
    #pragma unroll
    for (int j = 0; j < 8; ++j) u[j] = f2bf(acc[j]);
    *(ushort8*)&ws[KWQ_OFF + ((size_t)(c * 17 + ct) * 4 + k4) * 512 + (size_t)row * 8] = u;
  } else {
    const int mb  = b - 136;
    const int m0t = mb * 8;
    const int m   = m0t + (t >> 5);
    const int p8  = (t & 31) * 8;
    *(float4*)&tile[t * 4] = *(const float4*)(Wo + (size_t)m0t * 128 + t * 4);
    __syncthreads();
    const float* wo = &tile[(t >> 5) * 128];
    for (int d = 0; d < 128; d += 4) {
      float4 wv = *(const float4*)&wo[d];
      float4 va0 = *(const float4*)(vT + (d + 0) * 256 + p8);
      float4 vb0 = *(const float4*)(vT + (d + 0) * 256 + p8 + 4);
      float4 va1 = *(const float4*)(vT + (d + 1) * 256 + p8);
      float4 vb1 = *(const float4*)(vT + (d + 1) * 256 + p8 + 4);
      float4 va2 = *(const float4*)(vT + (d + 2) * 256 + p8);
      float4 vb2 = *(const float4*)(vT + (d + 2) * 256 + p8 + 4);
      float4 va3 = *(const float4*)(vT + (d + 3) * 256 + p8);
      float4 vb3 = *(const float4*)(vT + (d + 3) * 256 + p8 + 4);
      acc[0] += wv.x*va0.x + wv.y*va1.x + wv.z*va2.x + wv.w*va3.x;
      acc[1] += wv.x*va0.y + wv.y*va1.y + wv.z*va2.y + wv.w*va3.y;
      acc[2] += wv.x*va0.z + wv.y*va1.z + wv.z*va2.z + wv.w*va3.z;
      acc[3] += wv.x*va0.w + wv.y*va1.w + wv.z*va2.w + wv.w*va3.w;
      acc[4] += wv.x*vb0.x + wv.y*vb1.x + wv.z*vb2.x + wv.w*vb3.x;
      acc[5] += wv.x*vb0.y + wv.y*vb1.y + wv.z*vb2.y + wv.w*vb3.y;
      acc[6] += wv.x*vb0.z + wv.y*vb1.z + wv.z*vb2.z + wv.w*vb3.z;
      acc[7] += wv.x*vb0.w + wv.y*vb1.w + wv.z*vb2.w + wv.w*vb3.w;
    }
    const int ctg = m >> 4, k8 = p8 >> 5;
    const int row = ((p8 >> 3) & 3) * 16 + (m & 15);
    ushort8 u;
    #pragma unroll
    for (int j = 0; j < 8; ++j) u[j] = f2bf(acc[j]);
    *(ushort8*)&ws[VWO_OFF + ((size_t)(ctg * 8 + k8) * 512) + (size_t)row * 8] = u;
  }
}

// ---------------------------------------------------------------------------
// PHASE SPLIT of the round-1 fused kernel (fused measured 125.6us; every
// structural variant R2-R6 regressed). scores_kernel = R1 phases 1-2 verbatim;
// out_kernel = R1 phase 3 verbatim. The gated-P slab ([32768][256] bf16) is
// parked INSIDE `out` at columns 896..1023 of each token row (128 f32 hold
// 256 bf16). Safe: P row i is written only by scores-block i/32 and read only
// by out-block i/32, which stages it to LDS behind __syncthreads() BEFORE
// writing any of its rows; cross-kernel visibility = stream kernel ordering.
// Purpose: per-phase rocprof timing to target the dominant phase next.
// ---------------------------------------------------------------------------
#define LDX 136        // x-tile row stride, ushorts (128 + 8 pad)
#define LDSLAB 264     // attn slab row stride, ushorts (256 + 8 pad)

__global__ __launch_bounds__(256, 4) void scores_kernel(
    const float* __restrict__ x, const float* __restrict__ gate_b,
    const ushort_t* __restrict__ ws, float* __restrict__ out)
{
  __shared__ __align__(16) char smem[2 * 32 * LDX * 2 + 32 * 4 * 4 * 2 + 32 * 4];
  ushort_t* xt0      = (ushort_t*)smem;                       // [32][136]
  ushort_t* xt1      = xt0 + 32 * LDX;
  ushort_t* slab     = (ushort_t*)smem;                       // [32][264] (attn phase)
  float*    pmax     = (float*)(smem + 2 * 32 * LDX * 2);     // [32][4]
  float*    psum     = pmax + 128;                            // [32][4]
  float*    gate_lds = psum + 128;                            // [32]

  const int t = threadIdx.x, wid = t >> 6, lane = t & 63;
  const int quad = lane >> 4, l16 = lane & 15;
  const int tok0 = blockIdx.x * 32;

  f32x4 acc[2][5];
  #pragma unroll
  for (int rt = 0; rt < 2; ++rt)
    #pragma unroll
    for (int ctl = 0; ctl < 5; ++ctl) acc[rt][ctl] = (f32x4){0.f,0.f,0.f,0.f};

  // ---------------- scores GEMM: 8 chunks of BK=128, dbuf staging ----------
  #pragma unroll
  for (int i = 0; i < 4; ++i) {
    int flat = i * 1024 + t * 4;
    int row = flat >> 7, col = flat & 127;
    float4 fv = *(const float4*)(x + (size_t)(tok0 + row) * 1024 + col);
    unsigned int pk0 = pack2bf(fv.x, fv.y), pk1 = pack2bf(fv.z, fv.w);
    *(unsigned long long*)&xt0[row * LDX + col] =
        (unsigned long long)pk0 | ((unsigned long long)pk1 << 32);
  }
  __syncthreads();

  for (int c = 0; c < 8; ++c) {
    ushort_t* cur = (c & 1) ? xt1 : xt0;
    ushort_t* nxt = (c & 1) ? xt0 : xt1;
    float4 fv[4];
    if (c < 7) {           // issue next chunk's global loads early
      #pragma unroll
      for (int i = 0; i < 4; ++i) {
        int flat = i * 1024 + t * 4;
        int row = flat >> 7, col = flat & 127;
        fv[i] = *(const float4*)(x + (size_t)(tok0 + row) * 1024 + (c + 1) * 128 + col);
      }
    }
    #pragma unroll
    for (int k4 = 0; k4 < 4; ++k4) {
      short8 a[2];
      #pragma unroll
      for (int rt = 0; rt < 2; ++rt)
        a[rt] = *(const short8*)&cur[(rt * 16 + l16) * LDX + k4 * 32 + quad * 8];
      #pragma unroll
      for (int ctl = 0; ctl < 5; ++ctl) {
        if (ctl == 4 && wid != 3) continue;     // wave-uniform branch
        const int ct = wid * 4 + ctl;
        short8 bfr = *(const short8*)&ws[KWQ_OFF +
            ((size_t)(c * 17 + ct) * 4 + k4) * 512 + (size_t)lane * 8];
        #pragma unroll
        for (int rt = 0; rt < 2; ++rt) acc[rt][ctl] = MFMA16(a[rt], bfr, acc[rt][ctl]);
      }
    }
    if (c < 7) {           // pack + write next buffer, single barrier per chunk
      #pragma unroll
      for (int i = 0; i < 4; ++i) {
        int flat = i * 1024 + t * 4;
        int row = flat >> 7, col = flat & 127;
        unsigned int pk0 = pack2bf(fv[i].x, fv[i].y), pk1 = pack2bf(fv[i].z, fv[i].w);
        *(unsigned long long*)&nxt[row * LDX + col] =
            (unsigned long long)pk0 | ((unsigned long long)pk1 << 32);
      }
      __syncthreads();
    }
  }

  // ---------------- cross-wave softmax --------------------------------------
  const float SC = 0.08838834764831845f * 1.44269504088896f;  // 1/sqrt(128) * log2e
  #pragma unroll
  for (int rt = 0; rt < 2; ++rt)
    #pragma unroll
    for (int r = 0; r < 4; ++r) {
      float m = acc[rt][0][r];
      #pragma unroll
      for (int ctl = 1; ctl < 4; ++ctl) m = fmaxf(m, acc[rt][ctl][r]);
      #pragma unroll
      for (int msk = 1; msk < 16; msk <<= 1) m = fmaxf(m, __shfl_xor(m, msk, 64));
      if (l16 == 0) pmax[(rt * 16 + quad * 4 + r) * 4 + wid] = m;
    }
  __syncthreads();   // barrier: pmax complete (also closes last xt reads)
  float Mf[2][4];
  #pragma unroll
  for (int rt = 0; rt < 2; ++rt)
    #pragma unroll
    for (int r = 0; r < 4; ++r) {
      f32x4 pm = *(f32x4*)&pmax[(rt * 16 + quad * 4 + r) * 4];
      Mf[rt][r] = fmaxf(fmaxf(pm[0], pm[1]), fmaxf(pm[2], pm[3]));
    }
  float Sm[2][4];
  #pragma unroll
  for (int rt = 0; rt < 2; ++rt)
    #pragma unroll
    for (int r = 0; r < 4; ++r) Sm[rt][r] = 0.f;
  #pragma unroll
  for (int rt = 0; rt < 2; ++rt)
    #pragma unroll
    for (int ctl = 0; ctl < 4; ++ctl)
      #pragma unroll
      for (int r = 0; r < 4; ++r) {
        float e = exp2f((acc[rt][ctl][r] - Mf[rt][r]) * SC);
        acc[rt][ctl][r] = e;
        Sm[rt][r] += e;
      }
  #pragma unroll
  for (int rt = 0; rt < 2; ++rt)
    #pragma unroll
    for (int r = 0; r < 4; ++r) {
      #pragma unroll
      for (int msk = 1; msk < 16; msk <<= 1) Sm[rt][r] += __shfl_xor(Sm[rt][r], msk, 64);
    }
  if (l16 == 0) {
    #pragma unroll
    for (int rt = 0; rt < 2; ++rt)
      #pragma unroll
      for (int r = 0; r < 4; ++r)
        psum[(rt * 16 + quad * 4 + r) * 4 + wid] = Sm[rt][r];
    if (wid == 3) {
      float gb = gate_b[0];
      #pragma unroll
      for (int rt = 0; rt < 2; ++rt)
        #pragma unroll
        for (int r = 0; r < 4; ++r) {
          float lg = acc[rt][4][r] + gb;   // raw score, col 256 (l16==0)
          gate_lds[rt * 16 + quad * 4 + r] = 1.f / (1.f + __expf(-lg));
        }
    }
  }
  __syncthreads();   // barrier: psum + gate complete
  float scl[2][4];   // gate / sum  (gate folded into attn slab)
  #pragma unroll
  for (int rt = 0; rt < 2; ++rt)
    #pragma unroll
    for (int r = 0; r < 4; ++r) {
      f32x4 ps = *(f32x4*)&psum[(rt * 16 + quad * 4 + r) * 4];
      float g = gate_lds[rt * 16 + quad * 4 + r];
      scl[rt][r] = g / (ps[0] + ps[1] + ps[2] + ps[3]);
    }

  // attn*gate -> shared slab (each wave writes its ct columns)
  #pragma unroll
  for (int rt = 0; rt < 2; ++rt)
    #pragma unroll
    for (int ctl = 0; ctl < 4; ++ctl)
      #pragma unroll
      for (int r = 0; r < 4; ++r)
        slab[(rt * 16 + quad * 4 + r) * LDSLAB + (wid * 4 + ctl) * 16 + l16] =
            f2bf(acc[rt][ctl][r] * scl[rt][r]);
  __syncthreads();   // barrier: slab complete

  // ---------------- park gated-P in out[:, 896:1024] (coalesced) ------------
  #pragma unroll
  for (int j = 0; j < 4; ++j) {
    int flat = j * 1024 + t * 4;             // 4096 f32 slots = 32 rows x 128
    int row = flat >> 7, col = flat & 127;
    uint4 v = *(const uint4*)&slab[row * LDSLAB + col * 2];
    *(uint4*)&out[(size_t)(tok0 + row) * 1024 + 896 + col] = v;
  }
}

// ---------------------------------------------------------------------------
// out_kernel: stage this block's P rows from out[:,896:1024] into LDS
// (barrier), then R1's out-GEMM verbatim: wave w owns cols [w*256,+256).
// ---------------------------------------------------------------------------
__global__ __launch_bounds__(256, 4) void out_kernel(
    const ushort_t* __restrict__ ws, float* __restrict__ out)
{
  __shared__ __align__(16) ushort_t slab[32 * LDSLAB];
  const int t = threadIdx.x, wid = t >> 6, lane = t & 63;
  const int quad = lane >> 4, l16 = lane & 15;
  const int tok0 = blockIdx.x * 32;

  #pragma unroll
  for (int j = 0; j < 4; ++j) {
    int flat = j * 1024 + t * 4;
    int row = flat >> 7, col = flat & 127;
    uint4 v = *(const uint4*)&out[(size_t)(tok0 + row) * 1024 + 896 + col];
    *(uint4*)&slab[row * LDSLAB + col * 2] = v;
  }
  __syncthreads();   // P staged; all subsequent stores are ordered after this

  short8 af[2][8];
  #pragma unroll
  for (int rt = 0; rt < 2; ++rt)
    #pragma unroll
    for (int k8 = 0; k8 < 8; ++k8)
      af[rt][k8] = *(const short8*)&slab[(rt * 16 + l16) * LDSLAB + k8 * 32 + quad * 8];

  const int n0 = wid * 256;
  for (int nt = 0; nt < 16; ++nt) {
    const int ctg = (n0 >> 4) + nt;
    short8 bf[8];
    #pragma unroll
    for (int k8 = 0; k8 < 8; ++k8)
      bf[k8] = *(const short8*)&ws[VWO_OFF + ((size_t)(ctg * 8 + k8) * 512) + (size_t)lane * 8];
    f32x4 oa[2];
    #pragma unroll
    for (int rt = 0; rt < 2; ++rt) oa[rt] = (f32x4){0.f,0.f,0.f,0.f};
    #pragma unroll
    for (int rt = 0; rt < 2; ++rt)
      #pragma unroll
      for (int k8 = 0; k8 < 8; ++k8)
        oa[rt] = MFMA16(af[rt][k8], bf[k8], oa[rt]);
    #pragma unroll
    for (int rt = 0; rt < 2; ++rt)
      #pragma unroll
      for (int r = 0; r < 4; ++r)
        __builtin_nontemporal_store(oa[rt][r],
            &out[(size_t)(tok0 + rt * 16 + quad * 4 + r) * 1024 + n0 + nt * 16 + l16]);
  }
}

// ---------------------------------------------------------------------------
extern "C" void kernel_launch(void* const* d_in, const int* in_sizes, int n_in,
                              void* d_out, int out_size, void* d_ws, size_t ws_size,
                              hipStream_t stream) {
  const float* x    = (const float*)d_in[0];
  const float* prim = (const float*)d_in[1];
  const float* Wq   = (const float*)d_in[2];
  const float* Wk   = (const float*)d_in[3];
  const float* Wv   = (const float*)d_in[4];
  const float* Wo   = (const float*)d_in[5];
  const float* gw   = (const float*)d_in[6];
  const float* gb   = (const float*)d_in[7];
  float* out = (float*)d_out;
  ushort_t* ws = (ushort_t*)d_ws;

  prep1_kernel<<<256, 256, 0, stream>>>(prim, Wk, Wv, ws);
  prep2_kernel<<<264, 256, 0, stream>>>(Wq, Wo, gw, ws);
  scores_kernel<<<1024, 256, 0, stream>>>(x, gb, ws, out);
  out_kernel<<<1024, 256, 0, stream>>>(ws, out);
}

// Round 8
// 318.603 us; speedup vs baseline: 1.6345x; 1.0288x over previous
//
#include <hip/hip_runtime.h>
#include <hip/hip_bf16.h>

typedef unsigned short ushort_t;
typedef __attribute__((ext_vector_type(8))) short short8;
typedef __attribute__((ext_vector_type(8))) unsigned short ushort8;
typedef __attribute__((ext_vector_type(4))) float f32x4;
typedef __attribute__((ext_vector_type(4))) unsigned int u32x4;

#define MFMA16(a,b,c) __builtin_amdgcn_mfma_f32_16x16x32_bf16((a),(b),(c),0,0,0)

__device__ __forceinline__ ushort_t f2bf(float f) {
  unsigned int u = __builtin_bit_cast(unsigned int, f);
  u += 0x7FFFu + ((u >> 16) & 1u);
  return (ushort_t)(u >> 16);
}
__device__ __forceinline__ unsigned int pack2bf(float a, float b) {
  unsigned int ua = __builtin_bit_cast(unsigned int, a);
  unsigned int ub = __builtin_bit_cast(unsigned int, b);
  ua += 0x7FFFu + ((ua >> 16) & 1u);
  ub += 0x7FFFu + ((ub >> 16) & 1u);
  return (ua >> 16) | (ub & 0xFFFF0000u);
}
__device__ __forceinline__ short8 pack8(float4 lo, float4 hi) {
  u32x4 u;
  u.x = pack2bf(lo.x, lo.y); u.y = pack2bf(lo.z, lo.w);
  u.z = pack2bf(hi.x, hi.y); u.w = pack2bf(hi.z, hi.w);
  return __builtin_bit_cast(short8, u);
}
// HBM->LDS DMA, 16B/lane. LDS dest = wave-uniform base + lane*16 (m104);
// global src is per-lane (pre-swizzle the source to get swizzled LDS layout).
__device__ __forceinline__ void gl_lds16(const float* g, void* lds) {
  __builtin_amdgcn_global_load_lds(
      (__attribute__((address_space(1))) void*)(g),
      (__attribute__((address_space(3))) void*)(lds), 16, 0, 0);
}

// Problem dims
#define DMd 1024
#define DPd 128
#define PPd 256

// Workspace layout (ushort element offsets unless noted)
// KWqExt fragments: [chunk 8][ct 17][k4 4][lane 64][8]  (272 x 1024 bf16)
#define KWQ_OFF 0
#define KWQ_SIZE (8*17*4*512)          // 278528
// VWo fragments: [ctg 64][k8 8][lane 64][8]             (256 x 1024 bf16)
#define VWO_OFF KWQ_SIZE
#define VWO_SIZE (64*8*512)            // 262144
#define KV_BYTE_OFF ((size_t)(KWQ_SIZE + VWO_SIZE) * 2)  // then: k [256][128] f32, vT [128][256] f32

// ---------------------------------------------------------------------------
// prep1: k = prim @ Wk^T (row-major [256][128]) and vT = (prim @ Wv^T)^T
// ---------------------------------------------------------------------------
__global__ __launch_bounds__(256) void prep1_kernel(
    const float* __restrict__ prim, const float* __restrict__ Wk,
    const float* __restrict__ Wv, ushort_t* __restrict__ ws) {
  __shared__ __align__(16) float Wl[128 * 132];
  __shared__ __align__(16) float pl[2 * 128];
  const int t = threadIdx.x;
  const int mat = blockIdx.x & 1;
  const int p0 = (blockIdx.x >> 1) * 2;
  const float* W = mat ? Wv : Wk;
  #pragma unroll
  for (int i = 0; i < 16; ++i) {
    int w = (i * 256 + t) * 4;
    int row = w >> 7, col = w & 127;
    *(float4*)&Wl[row * 132 + col] = *(const float4*)(W + w);
  }
  if (t < 64) {
    int row = t >> 5, col = (t & 31) * 4;
    *(float4*)&pl[row * 128 + col] = *(const float4*)(prim + (p0 + row) * 128 + col);
  }
  __syncthreads();
  const int d = t & 127, slot = t >> 7;
  float a0 = 0.f, a1 = 0.f, a2 = 0.f, a3 = 0.f;
  #pragma unroll
  for (int j = 0; j < 128; j += 4) {
    float4 w4 = *(const float4*)&Wl[d * 132 + j];
    float4 p4 = *(const float4*)&pl[slot * 128 + j];
    a0 += w4.x * p4.x; a1 += w4.y * p4.y; a2 += w4.z * p4.z; a3 += w4.w * p4.w;
  }
  float r = (a0 + a1) + (a2 + a3);
  float* kf = (float*)((char*)ws + KV_BYTE_OFF);
  float* vT = kf + 32768;
  if (mat == 0) kf[(p0 + slot) * 128 + d] = r;
  else          vT[d * 256 + p0 + slot] = r;
}

// ---------------------------------------------------------------------------
// prep2: 264 blocks; emits frag-major KWqExt / VWo.
// ---------------------------------------------------------------------------
__global__ __launch_bounds__(256) void prep2_kernel(
    const float* __restrict__ Wq, const float* __restrict__ Wo,
    const float* __restrict__ gate_w, ushort_t* __restrict__ ws) {
  const float* kf = (const float*)((const char*)ws + KV_BYTE_OFF);
  const float* vT = kf + 32768;
  __shared__ __align__(16) float tile[8 * 128];
  const int b = blockIdx.x, t = threadIdx.x;
  float acc[8];
  #pragma unroll
  for (int j = 0; j < 8; ++j) acc[j] = 0.f;
  if (b < 136) {
    const int pt = b >> 2, ms = b & 3;
    const int p0 = pt * 8;
    const int p  = p0 + (t >> 5);
    const int m0 = ms * 256 + (t & 31) * 8;
    if (p0 < 256) {
      *(float4*)&tile[t * 4] = *(const float4*)(kf + p0 * 128 + t * 4);
      __syncthreads();
      const float* kp = &tile[(t >> 5) * 128];
      for (int d = 0; d < 128; d += 4) {
        float4 kv = *(const float4*)&kp[d];
        float4 qa0 = *(const float4*)(Wq + (d + 0) * 1024 + m0);
        float4 qb0 = *(const float4*)(Wq + (d + 0) * 1024 + m0 + 4);
        float4 qa1 = *(const float4*)(Wq + (d + 1) * 1024 + m0);
        float4 qb1 = *(const float4*)(Wq + (d + 1) * 1024 + m0 + 4);
        float4 qa2 = *(const float4*)(Wq + (d + 2) * 1024 + m0);
        float4 qb2 = *(const float4*)(Wq + (d + 2) * 1024 + m0 + 4);
        float4 qa3 = *(const float4*)(Wq + (d + 3) * 1024 + m0);
        float4 qb3 = *(const float4*)(Wq + (d + 3) * 1024 + m0 + 4);
        acc[0] += kv.x*qa0.x + kv.y*qa1.x + kv.z*qa2.x + kv.w*qa3.x;
        acc[1] += kv.x*qa0.y + kv.y*qa1.y + kv.z*qa2.y + kv.w*qa3.y;
        acc[2] += kv.x*qa0.z + kv.y*qa1.z + kv.z*qa2.z + kv.w*qa3.z;
        acc[3] += kv.x*qa0.w + kv.y*qa1.w + kv.z*qa2.w + kv.w*qa3.w;
        acc[4] += kv.x*qb0.x + kv.y*qb1.x + kv.z*qb2.x + kv.w*qb3.x;
        acc[5] += kv.x*qb0.y + kv.y*qb1.y + kv.z*qb2.y + kv.w*qb3.y;
        acc[6] += kv.x*qb0.z + kv.y*qb1.z + kv.z*qb2.z + kv.w*qb3.z;
        acc[7] += kv.x*qb0.w + kv.y*qb1.w + kv.z*qb2.w + kv.w*qb3.w;
      }
    } else if (p == 256) {
      #pragma unroll
      for (int j = 0; j < 8; ++j) acc[j] = gate_w[m0 + j];
    }
    const int c = m0 >> 7, ct = p >> 4, k4 = (m0 >> 5) & 3;
    const int row = ((m0 >> 3) & 3) * 16 + (p & 15);
    ushort8 u;
    #pragma unroll
    for (int j = 0; j < 8; ++j) u[j] = f2bf(acc[j]);
    *(ushort8*)&ws[KWQ_OFF + ((size_t)(c * 17 + ct) * 4 + k4) * 512 + (size_t)row * 8] = u;
  } else {
    const int mb  = b - 136;
    const int m0t = mb * 8;
    const int m   = m0t + (t >> 5);
    const int p8  = (t & 31) * 8;
    *(float4*)&tile[t * 4] = *(const float4*)(Wo + (size_t)m0t * 128 + t * 4);
    __syncthreads();
    const float* wo = &tile[(t >> 5) * 128];
    for (int d = 0; d < 128; d += 4) {
      float4 wv = *(const float4*)&wo[d];
      float4 va0 = *(const float4*)(vT + (d + 0) * 256 + p8);
      float4 vb0 = *(const float4*)(vT + (d + 0) * 256 + p8 + 4);
      float4 va1 = *(const float4*)(vT + (d + 1) * 256 + p8);
      float4 vb1 = *(const float4*)(vT + (d + 1) * 256 + p8 + 4);
      float4 va2 = *(const float4*)(vT + (d + 2) * 256 + p8);
      float4 vb2 = *(const float4*)(vT + (d + 2) * 256 + p8 + 4);
      float4 va3 = *(const float4*)(vT + (d + 3) * 256 + p8);
      float4 vb3 = *(const float4*)(vT + (d + 3) * 256 + p8 + 4);
      acc[0] += wv.x*va0.x + wv.y*va1.x + wv.z*va2.x + wv.w*va3.x;
      acc[1] += wv.x*va0.y + wv.y*va1.y + wv.z*va2.y + wv.w*va3.y;
      acc[2] += wv.x*va0.z + wv.y*va1.z + wv.z*va2.z + wv.w*va3.z;
      acc[3] += wv.x*va0.w + wv.y*va1.w + wv.z*va2.w + wv.w*va3.w;
      acc[4] += wv.x*vb0.x + wv.y*vb1.x + wv.z*vb2.x + wv.w*vb3.x;
      acc[5] += wv.x*vb0.y + wv.y*vb1.y + wv.z*vb2.y + wv.w*vb3.y;
      acc[6] += wv.x*vb0.z + wv.y*vb1.z + wv.z*vb2.z + wv.w*vb3.z;
      acc[7] += wv.x*vb0.w + wv.y*vb1.w + wv.z*vb2.w + wv.w*vb3.w;
    }
    const int ctg = m >> 4, k8 = p8 >> 5;
    const int row = ((p8 >> 3) & 3) * 16 + (m & 15);
    ushort8 u;
    #pragma unroll
    for (int j = 0; j < 8; ++j) u[j] = f2bf(acc[j]);
    *(ushort8*)&ws[VWO_OFF + ((size_t)(ctg * 8 + k8) * 512) + (size_t)row * 8] = u;
  }
}

// ---------------------------------------------------------------------------
// scores_kernel v2: x staged fp32 via global_load_lds DMA (no VGPR round-trip,
// no pack-before-store, no ds_write) into a double-buffered [32][128] f32 tile.
// Source-side G4 swizzle (byte ^= (row&7)<<4 within each 512B row) so the
// b128 LDS reads run at the bank floor. bf16 pack moved into the k4 body.
// Gate tile computed uniformly by all waves (dead for wid<3) -> branch-free
// straight-line chunk body. Softmax / P-park identical to round 7.
// ---------------------------------------------------------------------------
#define LDSLAB 264     // attn slab row stride, ushorts (256 + 8 pad)

__global__ __launch_bounds__(256, 4) void scores_kernel(
    const float* __restrict__ x, const float* __restrict__ gate_b,
    const ushort_t* __restrict__ ws, float* __restrict__ out)
{
  // xf0/xf1: [32][128] fp32 (col-swizzled), 16KB each; slab aliases them.
  __shared__ __align__(16) char smem[32768 + 32 * 4 * 4 * 2 + 32 * 4];
  char*     xb0      = smem;                 // 16384 B
  char*     xb1      = smem + 16384;         // 16384 B
  ushort_t* slab     = (ushort_t*)smem;      // [32][264] (attn phase, aliases)
  float*    pmax     = (float*)(smem + 32768);   // [32][4]
  float*    psum     = pmax + 128;               // [32][4]
  float*    gate_lds = psum + 128;               // [32]

  const int t = threadIdx.x, wid = t >> 6, lane = t & 63;
  const int quad = lane >> 4, l16 = lane & 15;
  const int tok0 = blockIdx.x * 32;
  const int ct0 = wid * 4;

  f32x4 acc[2][5];
  #pragma unroll
  for (int rt = 0; rt < 2; ++rt)
    #pragma unroll
    for (int ctl = 0; ctl < 5; ++ctl) acc[rt][ctl] = (f32x4){0.f,0.f,0.f,0.f};

  // staging geometry (per thread, invariant over chunks)
  // issue i: LDS byte o = (wid*4+i)*1024 + lane*16; row = o>>9; cb = o&511.
  int srow[4], scol[4], sobase[4];
  #pragma unroll
  for (int i = 0; i < 4; ++i) {
    int obase = (wid * 4 + i) * 1024;
    int o = obase + lane * 16;
    int row = o >> 9;
    int cb  = o & 511;
    int scb = cb ^ ((row & 7) << 4);    // pre-swizzled source column (bytes)
    srow[i] = row; scol[i] = scb >> 2; sobase[i] = obase;
  }

  #define STAGE(buf, cc)                                                       \
    {                                                                          \
      _Pragma("unroll")                                                        \
      for (int i = 0; i < 4; ++i)                                              \
        gl_lds16(x + (size_t)(tok0 + srow[i]) * 1024 + (cc) * 128 + scol[i],   \
                 (buf) + sobase[i]);                                           \
    }

  // read-path constants: row0 = l16, row1 = 16+l16; (row&7) identical.
  const int f    = (l16 & 7) << 4;
  const int rb0  = l16 * 512;
  const int rb1  = (16 + l16) * 512;

  // prologue: stage chunk 0
  STAGE(xb0, 0)
  __syncthreads();

  for (int c = 0; c < 8; ++c) {
    const char* xb = (c & 1) ? xb1 : xb0;
    char*      nxt = (c & 1) ? xb0 : xb1;
    if (c < 7) STAGE(nxt, c + 1)       // DMA in flight across the whole chunk
    const ushort_t* wb = ws + KWQ_OFF + (size_t)(c * 17) * 4 * 512 + (size_t)lane * 8;
    #pragma unroll
    for (int k4 = 0; k4 < 4; ++k4) {
      const int cb0 = k4 * 128 + quad * 32;
      float4 a0lo = *(const float4*)(xb + rb0 + ((cb0     ) ^ f));
      float4 a0hi = *(const float4*)(xb + rb0 + ((cb0 + 16) ^ f));
      float4 a1lo = *(const float4*)(xb + rb1 + ((cb0     ) ^ f));
      float4 a1hi = *(const float4*)(xb + rb1 + ((cb0 + 16) ^ f));
      short8 b0 = *(const short8*)&wb[(size_t)((ct0 + 0) * 4 + k4) * 512];
      short8 b1 = *(const short8*)&wb[(size_t)((ct0 + 1) * 4 + k4) * 512];
      short8 b2 = *(const short8*)&wb[(size_t)((ct0 + 2) * 4 + k4) * 512];
      short8 b3 = *(const short8*)&wb[(size_t)((ct0 + 3) * 4 + k4) * 512];
      short8 b4 = *(const short8*)&wb[(size_t)((ct0 + 4) * 4 + k4) * 512];
      short8 a0 = pack8(a0lo, a0hi);
      short8 a1 = pack8(a1lo, a1hi);
      acc[0][0] = MFMA16(a0, b0, acc[0][0]);
      acc[1][0] = MFMA16(a1, b0, acc[1][0]);
      acc[0][1] = MFMA16(a0, b1, acc[0][1]);
      acc[1][1] = MFMA16(a1, b1, acc[1][1]);
      acc[0][2] = MFMA16(a0, b2, acc[0][2]);
      acc[1][2] = MFMA16(a1, b2, acc[1][2]);
      acc[0][3] = MFMA16(a0, b3, acc[0][3]);
      acc[1][3] = MFMA16(a1, b3, acc[1][3]);
      acc[0][4] = MFMA16(a0, b4, acc[0][4]);
      acc[1][4] = MFMA16(a1, b4, acc[1][4]);
    }
    __syncthreads();   // vmcnt(0)+barrier: next buffer's DMA landed
  }

  // ---------------- cross-wave softmax --------------------------------------
  const float SC = 0.08838834764831845f * 1.44269504088896f;  // 1/sqrt(128) * log2e
  #pragma unroll
  for (int rt = 0; rt < 2; ++rt)
    #pragma unroll
    for (int r = 0; r < 4; ++r) {
      float m = acc[rt][0][r];
      #pragma unroll
      for (int ctl = 1; ctl < 4; ++ctl) m = fmaxf(m, acc[rt][ctl][r]);
      #pragma unroll
      for (int msk = 1; msk < 16; msk <<= 1) m = fmaxf(m, __shfl_xor(m, msk, 64));
      if (l16 == 0) pmax[(rt * 16 + quad * 4 + r) * 4 + wid] = m;
    }
  __syncthreads();   // pmax complete
  float Mf[2][4];
  #pragma unroll
  for (int rt = 0; rt < 2; ++rt)
    #pragma unroll
    for (int r = 0; r < 4; ++r) {
      f32x4 pm = *(f32x4*)&pmax[(rt * 16 + quad * 4 + r) * 4];
      Mf[rt][r] = fmaxf(fmaxf(pm[0], pm[1]), fmaxf(pm[2], pm[3]));
    }
  float Sm[2][4];
  #pragma unroll
  for (int rt = 0; rt < 2; ++rt)
    #pragma unroll
    for (int r = 0; r < 4; ++r) Sm[rt][r] = 0.f;
  #pragma unroll
  for (int rt = 0; rt < 2; ++rt)
    #pragma unroll
    for (int ctl = 0; ctl < 4; ++ctl)
      #pragma unroll
      for (int r = 0; r < 4; ++r) {
        float e = exp2f((acc[rt][ctl][r] - Mf[rt][r]) * SC);
        acc[rt][ctl][r] = e;
        Sm[rt][r] += e;
      }
  #pragma unroll
  for (int rt = 0; rt < 2; ++rt)
    #pragma unroll
    for (int r = 0; r < 4; ++r) {
      #pragma unroll
      for (int msk = 1; msk < 16; msk <<= 1) Sm[rt][r] += __shfl_xor(Sm[rt][r], msk, 64);
    }
  if (l16 == 0) {
    #pragma unroll
    for (int rt = 0; rt < 2; ++rt)
      #pragma unroll
      for (int r = 0; r < 4; ++r)
        psum[(rt * 16 + quad * 4 + r) * 4 + wid] = Sm[rt][r];
    if (wid == 3) {
      float gb = gate_b[0];
      #pragma unroll
      for (int rt = 0; rt < 2; ++rt)
        #pragma unroll
        for (int r = 0; r < 4; ++r) {
          float lg = acc[rt][4][r] + gb;   // raw score, col 256 (l16==0)
          gate_lds[rt * 16 + quad * 4 + r] = 1.f / (1.f + __expf(-lg));
        }
    }
  }
  __syncthreads();   // psum + gate complete
  float scl[2][4];   // gate / sum (gate folded into slab)
  #pragma unroll
  for (int rt = 0; rt < 2; ++rt)
    #pragma unroll
    for (int r = 0; r < 4; ++r) {
      f32x4 ps = *(f32x4*)&psum[(rt * 16 + quad * 4 + r) * 4];
      float g = gate_lds[rt * 16 + quad * 4 + r];
      scl[rt][r] = g / (ps[0] + ps[1] + ps[2] + ps[3]);
    }

  // attn*gate -> shared slab (each wave writes its 4 ct columns)
  #pragma unroll
  for (int rt = 0; rt < 2; ++rt)
    #pragma unroll
    for (int ctl = 0; ctl < 4; ++ctl)
      #pragma unroll
      for (int r = 0; r < 4; ++r)
        slab[(rt * 16 + quad * 4 + r) * LDSLAB + (ct0 + ctl) * 16 + l16] =
            f2bf(acc[rt][ctl][r] * scl[rt][r]);
  __syncthreads();   // slab complete

  // ---------------- park gated-P in out[:, 896:1024] (coalesced) ------------
  #pragma unroll
  for (int j = 0; j < 4; ++j) {
    int flat = j * 1024 + t * 4;             // 4096 f32 slots = 32 rows x 128
    int row = flat >> 7, col = flat & 127;
    uint4 v = *(const uint4*)&slab[row * LDSLAB + col * 2];
    *(uint4*)&out[(size_t)(tok0 + row) * 1024 + 896 + col] = v;
  }
}

// ---------------------------------------------------------------------------
// out_kernel: stage this block's P rows from out[:,896:1024] into LDS
// (barrier), then the out-GEMM: wave w owns cols [w*256,+256).
// ---------------------------------------------------------------------------
__global__ __launch_bounds__(256, 4) void out_kernel(
    const ushort_t* __restrict__ ws, float* __restrict__ out)
{
  __shared__ __align__(16) ushort_t slab[32 * LDSLAB];
  const int t = threadIdx.x, wid = t >> 6, lane = t & 63;
  const int quad = lane >> 4, l16 = lane & 15;
  const int tok0 = blockIdx.x * 32;

  #pragma unroll
  for (int j = 0; j < 4; ++j) {
    int flat = j * 1024 + t * 4;
    int row = flat >> 7, col = flat & 127;
    uint4 v = *(const uint4*)&out[(size_t)(tok0 + row) * 1024 + 896 + col];
    *(uint4*)&slab[row * LDSLAB + col * 2] = v;
  }
  __syncthreads();   // P staged; all subsequent stores are ordered after this

  short8 af[2][8];
  #pragma unroll
  for (int rt = 0; rt < 2; ++rt)
    #pragma unroll
    for (int k8 = 0; k8 < 8; ++k8)
      af[rt][k8] = *(const short8*)&slab[(rt * 16 + l16) * LDSLAB + k8 * 32 + quad * 8];

  const int n0 = wid * 256;
  for (int nt = 0; nt < 16; ++nt) {
    const int ctg = (n0 >> 4) + nt;
    short8 bf[8];
    #pragma unroll
    for (int k8 = 0; k8 < 8; ++k8)
      bf[k8] = *(const short8*)&ws[VWO_OFF + ((size_t)(ctg * 8 + k8) * 512) + (size_t)lane * 8];
    f32x4 oa[2];
    #pragma unroll
    for (int rt = 0; rt < 2; ++rt) oa[rt] = (f32x4){0.f,0.f,0.f,0.f};
    #pragma unroll
    for (int rt = 0; rt < 2; ++rt)
      #pragma unroll
      for (int k8 = 0; k8 < 8; ++k8)
        oa[rt] = MFMA16(af[rt][k8], bf[k8], oa[rt]);
    #pragma unroll
    for (int rt = 0; rt < 2; ++rt)
      #pragma unroll
      for (int r = 0; r < 4; ++r)
        __builtin_nontemporal_store(oa[rt][r],
            &out[(size_t)(tok0 + rt * 16 + quad * 4 + r) * 1024 + n0 + nt * 16 + l16]);
  }
}

// ---------------------------------------------------------------------------
extern "C" void kernel_launch(void* const* d_in, const int* in_sizes, int n_in,
                              void* d_out, int out_size, void* d_ws, size_t ws_size,
                              hipStream_t stream) {
  const float* x    = (const float*)d_in[0];
  const float* prim = (const float*)d_in[1];
  const float* Wq   = (const float*)d_in[2];
  const float* Wk   = (const float*)d_in[3];
  const float* Wv   = (const float*)d_in[4];
  const float* Wo   = (const float*)d_in[5];
  const float* gw   = (const float*)d_in[6];
  const float* gb   = (const float*)d_in[7];
  float* out = (float*)d_out;
  ushort_t* ws = (ushort_t*)d_ws;

  prep1_kernel<<<256, 256, 0, stream>>>(prim, Wk, Wv, ws);
  prep2_kernel<<<264, 256, 0, stream>>>(Wq, Wo, gw, ws);
  scores_kernel<<<1024, 256, 0, stream>>>(x, gb, ws, out);
  out_kernel<<<1024, 256, 0, stream>>>(ws, out);
}